// Round 3
// baseline (1738.225 us; speedup 1.0000x reference)
//
#include <hip/hip_runtime.h>
#include <math.h>

#define NTOK   131040   // 8*91*180
#define NTOKW  138240   // 15*64*144

typedef __attribute__((ext_vector_type(8))) short bf16x8;
typedef __attribute__((ext_vector_type(8))) unsigned short u16x8;
typedef __attribute__((ext_vector_type(4))) float f32x4;

__device__ __forceinline__ float b2f(unsigned short u){
  union { unsigned u; float f; } v; v.u = ((unsigned)u) << 16; return v.f;
}
__device__ __forceinline__ unsigned short f2b(float f){
  union { float f; unsigned u; } v; v.f = f;
  unsigned r = v.u + 0x7FFFu + ((v.u >> 16) & 1u);
  return (unsigned short)(r >> 16);
}

// transpose-cast: dst[n][k] = (bf16)src[k][n]   (dst is [N][K])
__global__ __launch_bounds__(256) void transp(const float* __restrict__ src,
                                              unsigned short* __restrict__ dst,
                                              int K, int N){
  int i = blockIdx.x*256 + threadIdx.x;
  if (i < K*N){
    int n = i / K, k = i % K;
    dst[i] = f2b(src[(size_t)k*N + n]);
  }
}

// window-partition gather (+pad +roll), fp32 -> bf16
__global__ __launch_bounds__(256) void gather_win(const float* __restrict__ x,
                                                  unsigned short* __restrict__ xw,
                                                  int roll){
  int gid = blockIdx.x*256 + threadIdx.x;
  int row = gid / 24;
  int dp  = gid % 24;
  int tok = row % 144;
  int wt  = row / 144;          // w*64+tw
  int tw  = wt & 63;
  int w   = wt >> 6;
  int nz = tw >> 4, nh = tw & 15;
  int wz = tok / 72; int rem = tok % 72; int wh = rem / 12; int ww = rem % 12;
  int z = nz*2 + wz, h = nh*6 + wh, wc = w*12 + ww;
  if (roll){ z = (z+1)&7; h = (h+3)%96; wc = (wc+6)%180; }
  int d0 = dp*8;
  u16x8 o;
  if (h < 91){
    const float* s = x + ((size_t)((z*91 + h)*180 + wc))*192 + d0;
    #pragma unroll
    for (int i=0;i<8;i++) o[i] = f2b(s[i]);
  } else {
    #pragma unroll
    for (int i=0;i<8;i++) o[i] = 0;
  }
  *(u16x8*)(xw + (size_t)row*192 + d0) = o;
}

// bf16 MFMA GEMM: C[MxN] = A[MxK] @ Bt[NxK]^T + bias   (K multiple of 32)
__global__ __launch_bounds__(256) void gemm_bf16(
    const unsigned short* __restrict__ A,
    const unsigned short* __restrict__ Bt,
    const float* __restrict__ bias,
    unsigned short* __restrict__ C,
    int M, int N, int K)
{
  __shared__ unsigned short As[128][40];
  __shared__ unsigned short Bst[64][40];   // [col][k]
  int m0 = blockIdx.x * 128;
  int n0 = blockIdx.y * 64;
  int t = threadIdx.x;
  int lane = t & 63, wid = t >> 6;
  int wm = wid >> 1, wn = wid & 1;
  int lg = lane >> 4, lr = lane & 15;
  f32x4 acc[4][2];
  #pragma unroll
  for (int a=0;a<4;a++)
    #pragma unroll
    for (int b=0;b<2;b++) acc[a][b] = (f32x4){0.f,0.f,0.f,0.f};

  int arow = t >> 1, ac0 = (t & 1) * 16;
  int bcol = t >> 2, bk = (t & 3) * 8;

  for (int k0 = 0; k0 < K; k0 += 32){
    {
      int gr = m0 + arow;
      u16x8 v0, v1;
      if (gr < M){
        const unsigned short* src = A + (size_t)gr*K + k0 + ac0;
        v0 = *(const u16x8*)src;
        v1 = *(const u16x8*)(src+8);
      } else {
        #pragma unroll
        for (int i=0;i<8;i++){ v0[i]=0; v1[i]=0; }
      }
      *(u16x8*)&As[arow][ac0]   = v0;
      *(u16x8*)&As[arow][ac0+8] = v1;
    }
    {
      u16x8 vb = *(const u16x8*)(Bt + (size_t)(n0 + bcol)*K + k0 + bk);
      *(u16x8*)&Bst[bcol][bk] = vb;
    }
    __syncthreads();
    #pragma unroll
    for (int fn=0; fn<2; fn++){
      bf16x8 bfr = *(const bf16x8*)&Bst[wn*32 + fn*16 + lr][lg*8];
      #pragma unroll
      for (int fm=0; fm<4; fm++){
        bf16x8 afr = *(const bf16x8*)&As[wm*64 + fm*16 + lr][lg*8];
        acc[fm][fn] = __builtin_amdgcn_mfma_f32_16x16x32_bf16(afr, bfr, acc[fm][fn], 0,0,0);
      }
    }
    __syncthreads();
  }
  #pragma unroll
  for (int fm=0; fm<4; fm++){
    #pragma unroll
    for (int fn=0; fn<2; fn++){
      #pragma unroll
      for (int r=0;r<4;r++){
        int rowg = m0 + wm*64 + fm*16 + lg*4 + r;
        int colg = n0 + wn*32 + fn*16 + lr;
        if (rowg < M){
          C[(size_t)rowg*N + colg] = f2b(acc[fm][fn][r] + bias[colg]);
        }
      }
    }
  }
}

// fused windowed attention: one block per (window-pair, head). 9 waves.
__global__ __launch_bounds__(576) void attn_win(
    const unsigned short* __restrict__ qkv,   // [NTOKW][576]
    const float* __restrict__ btab,           // [3312][64][6] (depth-sliced)
    unsigned short* __restrict__ outp,        // [NTOKW][192]
    int roll)
{
  __shared__ unsigned short Qs[144][32];
  __shared__ unsigned short Ks[144][40];
  __shared__ unsigned short Vst[32][168];
  __shared__ unsigned short Ps[144][168];

  int b = blockIdx.x;
  int head = b % 6;
  int wt = b / 6;          // w*64+tw
  int tw = wt & 63;
  int t = threadIdx.x;
  int lane = t & 63;
  int wv = t >> 6;         // 0..8
  int lg = lane >> 4, lr = lane & 15;

  {
    int tok = t >> 2, c0 = (t & 3)*8;
    size_t base = ((size_t)wt*144 + tok)*576 + head*32 + c0;
    u16x8 qv = *(const u16x8*)(qkv + base);
    u16x8 kv = *(const u16x8*)(qkv + base + 192);
    u16x8 vv = *(const u16x8*)(qkv + base + 384);
    u16x8 qs;
    #pragma unroll
    for (int i=0;i<8;i++) qs[i] = f2b(b2f(qv[i]) * 0.17677669529663687f);
    *(u16x8*)&Qs[tok][c0] = qs;
    *(u16x8*)&Ks[tok][c0] = kv;
    #pragma unroll
    for (int i=0;i<8;i++) Vst[c0+i][tok] = vv[i];
  }
  if (t < 512) Vst[t >> 4][144 + (t & 15)] = 0;
  __syncthreads();

  float s[9][4];
  {
    bf16x8 a = *(const bf16x8*)&Qs[wv*16 + lr][lg*8];
    #pragma unroll
    for (int ct=0; ct<9; ct++){
      bf16x8 bb = *(const bf16x8*)&Ks[ct*16 + lr][lg*8];
      f32x4 d = {0.f,0.f,0.f,0.f};
      d = __builtin_amdgcn_mfma_f32_16x16x32_bf16(a, bb, d, 0,0,0);
      s[ct][0]=d[0]; s[ct][1]=d[1]; s[ct][2]=d[2]; s[ct][3]=d[3];
    }
  }

  int nz = tw >> 4, nh = tw & 15;
  int ia[4], ib[4], ic[4], ridi[4];
  #pragma unroll
  for (int r=0;r<4;r++){
    int i = wv*16 + lg*4 + r;
    ia[r] = i/72; int rem = i%72; ib[r] = rem/12; ic[r] = rem%12;
    int z = nz*2 + ia[r], h = nh*6 + ib[r];
    ridi[r] = 3*((z<6)?0:((z<7)?1:2)) + ((h<90)?0:((h<93)?1:2));
  }
  #pragma unroll
  for (int ct=0; ct<9; ct++){
    int j = ct*16 + lr;
    int ja = j/72; int jrem = j%72; int jb = jrem/12; int jc = jrem%12;
    int zj = nz*2 + ja, hj = nh*6 + jb;
    int ridj = 3*((zj<6)?0:((zj<7)?1:2)) + ((hj<90)?0:((hj<93)?1:2));
    #pragma unroll
    for (int r=0;r<4;r++){
      int idx = (ia[r] + 2*ja)*828 + (ib[r] + 6*jb)*23 + (ic[r] - jc + 11);
      float add = btab[(size_t)idx*384 + tw*6 + head];
      if (roll && (ridi[r] != ridj)) add -= 100.0f;
      s[ct][r] += add;
    }
  }

  float mx[4] = {-1e30f,-1e30f,-1e30f,-1e30f};
  #pragma unroll
  for (int ct=0; ct<9; ct++)
    #pragma unroll
    for (int r=0;r<4;r++) mx[r] = fmaxf(mx[r], s[ct][r]);
  #pragma unroll
  for (int off=1; off<16; off<<=1)
    #pragma unroll
    for (int r=0;r<4;r++) mx[r] = fmaxf(mx[r], __shfl_xor(mx[r], off));
  float sm[4] = {0.f,0.f,0.f,0.f};
  #pragma unroll
  for (int ct=0; ct<9; ct++)
    #pragma unroll
    for (int r=0;r<4;r++){ s[ct][r] = __expf(s[ct][r] - mx[r]); sm[r] += s[ct][r]; }
  #pragma unroll
  for (int off=1; off<16; off<<=1)
    #pragma unroll
    for (int r=0;r<4;r++) sm[r] += __shfl_xor(sm[r], off);
  float inv[4];
  #pragma unroll
  for (int r=0;r<4;r++) inv[r] = 1.0f / sm[r];
  #pragma unroll
  for (int ct=0; ct<9; ct++)
    #pragma unroll
    for (int r=0;r<4;r++)
      Ps[wv*16 + lg*4 + r][ct*16 + lr] = f2b(s[ct][r] * inv[r]);
  #pragma unroll
  for (int r=0;r<4;r++) Ps[wv*16 + lg*4 + r][144 + lr] = 0;
  __syncthreads();

  #pragma unroll
  for (int ct2=0; ct2<2; ct2++){
    f32x4 o = {0.f,0.f,0.f,0.f};
    #pragma unroll
    for (int kt=0; kt<5; kt++){
      bf16x8 a  = *(const bf16x8*)&Ps[wv*16 + lr][kt*32 + lg*8];
      bf16x8 bb = *(const bf16x8*)&Vst[ct2*16 + lr][kt*32 + lg*8];
      o = __builtin_amdgcn_mfma_f32_16x16x32_bf16(a, bb, o, 0,0,0);
    }
    size_t rb = ((size_t)wt*144 + wv*16 + lg*4)*192 + head*32 + ct2*16 + lr;
    #pragma unroll
    for (int r=0;r<4;r++) outp[rb + (size_t)r*192] = f2b(o[r]);
  }
}

// un-window (+unroll +crop) + LN + residual; writes fp32 trunk + bf16 copy
__global__ __launch_bounds__(256) void unwin_ln(
  const unsigned short* __restrict__ ywin,
  const float* __restrict__ xsrc,
  const float* __restrict__ g, const float* __restrict__ bb,
  float* __restrict__ outf, unsigned short* __restrict__ outb, int roll)
{
  int tok = blockIdx.x*4 + (threadIdx.x>>6);
  if (tok >= NTOK) return;
  int lane = threadIdx.x & 63;
  int z = tok / (91*180);
  int rem = tok % (91*180);
  int h = rem / 180, wc = rem % 180;
  int zz=z, hh=h, ww=wc;
  if (roll){ zz = (z+7)&7; hh = (h+93)%96; ww = (wc+174)%180; }
  int nz = zz>>1, wz = zz&1;
  int nh = hh/6,  wh = hh%6;
  int nw = ww/12, w2 = ww%12;
  size_t row = ((size_t)(nw*64 + nz*16 + nh))*144 + wz*72 + wh*12 + w2;
  const unsigned short* yr = ywin + row*192;
  float v[3]; float s=0.f, ss=0.f;
  #pragma unroll
  for (int i=0;i<3;i++){ v[i] = b2f(yr[lane + i*64]); s += v[i]; ss += v[i]*v[i]; }
  #pragma unroll
  for (int off=32; off>=1; off>>=1){ s += __shfl_xor(s, off); ss += __shfl_xor(ss, off); }
  float mean = s * (1.0f/192.0f);
  float var = ss * (1.0f/192.0f) - mean*mean;
  float rinv = rsqrtf(var + 1e-5f);
  size_t tb = (size_t)tok*192;
  #pragma unroll
  for (int i=0;i<3;i++){
    int d = lane + i*64;
    float o = xsrc[tb + d] + ((v[i]-mean)*rinv*g[d] + bb[d]);
    outf[tb+d] = o;
    outb[tb+d] = f2b(o);
  }
}

// fused MLP: C = gelu(A @ W1 + b1) @ W2 + b2, hidden chunked by 32
__global__ __launch_bounds__(256) void mlp_fused(
    const unsigned short* __restrict__ A,    // [M][192]
    const unsigned short* __restrict__ W1t,  // [768][192]
    const float* __restrict__ b1,            // [768]
    const unsigned short* __restrict__ W2t,  // [192][768]
    const float* __restrict__ b2,            // [192]
    unsigned short* __restrict__ C,          // [M][192]
    int M)
{
  __shared__ unsigned short As [64][200];
  __shared__ unsigned short W1s[32][200];
  __shared__ unsigned short W2s[192][40];
  __shared__ unsigned short Hs [64][40];
  int m0 = blockIdx.x*64;
  int t = threadIdx.x; int lane = t & 63; int w = t >> 6;
  int lg = lane >> 4, lr = lane & 15;

  #pragma unroll
  for (int i=0;i<6;i++){
    int idx = t + i*256;            // 0..1535
    int r = idx / 24, c0 = (idx % 24)*8;
    int gr = m0 + r;
    u16x8 v;
    if (gr < M){
      v = *(const u16x8*)(A + (size_t)gr*192 + c0);
    } else {
      for (int j=0;j<8;j++) v[j]=0;
    }
    *(u16x8*)&As[r][c0] = v;
  }

  f32x4 acc[4][3];
  #pragma unroll
  for (int a=0;a<4;a++)
    #pragma unroll
    for (int b=0;b<3;b++) acc[a][b] = (f32x4){0.f,0.f,0.f,0.f};

  int colt = w & 1, rh = w >> 1;

  for (int hc = 0; hc < 768; hc += 32){
    #pragma unroll
    for (int i=0;i<3;i++){
      int idx = t + i*256;          // 0..767
      int r = idx / 24, c0 = (idx % 24)*8;
      *(u16x8*)&W1s[r][c0] = *(const u16x8*)(W1t + (size_t)(hc + r)*192 + c0);
    }
    #pragma unroll
    for (int i=0;i<3;i++){
      int idx = t + i*256;          // 0..767
      int r = idx / 4, c0 = (idx & 3)*8;
      *(u16x8*)&W2s[r][c0] = *(const u16x8*)(W2t + (size_t)r*768 + hc + c0);
    }
    __syncthreads();

    f32x4 h[2];
    h[0] = (f32x4){0.f,0.f,0.f,0.f};
    h[1] = (f32x4){0.f,0.f,0.f,0.f};
    #pragma unroll
    for (int ks=0; ks<6; ks++){
      bf16x8 bfr = *(const bf16x8*)&W1s[colt*16 + lr][ks*32 + lg*8];
      #pragma unroll
      for (int fm=0; fm<2; fm++){
        bf16x8 afr = *(const bf16x8*)&As[rh*32 + fm*16 + lr][ks*32 + lg*8];
        h[fm] = __builtin_amdgcn_mfma_f32_16x16x32_bf16(afr, bfr, h[fm], 0,0,0);
      }
    }
    #pragma unroll
    for (int fm=0; fm<2; fm++)
      #pragma unroll
      for (int r=0;r<4;r++){
        float v = h[fm][r] + b1[hc + colt*16 + lr];
        v = 0.5f*v*(1.0f + erff(v*0.70710678118654752f));
        Hs[rh*32 + fm*16 + lg*4 + r][colt*16 + lr] = f2b(v);
      }
    __syncthreads();

    #pragma unroll
    for (int fn=0; fn<3; fn++){
      bf16x8 bfr = *(const bf16x8*)&W2s[w*48 + fn*16 + lr][lg*8];
      #pragma unroll
      for (int fm=0; fm<4; fm++){
        bf16x8 afr = *(const bf16x8*)&Hs[fm*16 + lr][lg*8];
        acc[fm][fn] = __builtin_amdgcn_mfma_f32_16x16x32_bf16(afr, bfr, acc[fm][fn], 0,0,0);
      }
    }
    __syncthreads();
  }

  #pragma unroll
  for (int fm=0; fm<4; fm++)
    #pragma unroll
    for (int fn=0; fn<3; fn++)
      #pragma unroll
      for (int r=0;r<4;r++){
        int rowg = m0 + fm*16 + lg*4 + r;
        int colg = w*48 + fn*16 + lr;
        if (rowg < M) C[(size_t)rowg*192 + colg] = f2b(acc[fm][fn][r] + b2[colg]);
      }
}

// out = xmid + LN(ymlp)
__global__ __launch_bounds__(256) void add_ln(
  const unsigned short* __restrict__ ymlp,
  const float* __restrict__ xmid,
  const float* __restrict__ g, const float* __restrict__ bb,
  float* __restrict__ outf)
{
  int tok = blockIdx.x*4 + (threadIdx.x>>6);
  if (tok >= NTOK) return;
  int lane = threadIdx.x & 63;
  const unsigned short* yr = ymlp + (size_t)tok*192;
  float v[3]; float s=0.f, ss=0.f;
  #pragma unroll
  for (int i=0;i<3;i++){ v[i] = b2f(yr[lane + i*64]); s += v[i]; ss += v[i]*v[i]; }
  #pragma unroll
  for (int off=32; off>=1; off>>=1){ s += __shfl_xor(s, off); ss += __shfl_xor(ss, off); }
  float mean = s * (1.0f/192.0f);
  float var = ss * (1.0f/192.0f) - mean*mean;
  float rinv = rsqrtf(var + 1e-5f);
  size_t tb = (size_t)tok*192;
  #pragma unroll
  for (int i=0;i<3;i++){
    int d = lane + i*64;
    outf[tb+d] = xmid[tb + d] + ((v[i]-mean)*rinv*g[d] + bb[d]);
  }
}

extern "C" void kernel_launch(void* const* d_in, const int* in_sizes, int n_in,
                              void* d_out, int out_size, void* d_ws, size_t ws_size,
                              hipStream_t stream)
{
  const float* x_in    = (const float*)d_in[0];
  const float* qkvw    = (const float*)d_in[1];
  const float* qkvbias = (const float*)d_in[2];
  const float* projw   = (const float*)d_in[3];
  const float* projbias= (const float*)d_in[4];
  const float* btab    = (const float*)d_in[5];
  const float* n1g = (const float*)d_in[6];
  const float* n1b = (const float*)d_in[7];
  const float* n2g = (const float*)d_in[8];
  const float* n2b = (const float*)d_in[9];
  const float* w1  = (const float*)d_in[10];
  const float* b1  = (const float*)d_in[11];
  const float* w2  = (const float*)d_in[12];
  const float* b2  = (const float*)d_in[13];
  float* outp = (float*)d_out;

  // workspace layout (shorts)
  const size_t REG_A = (size_t)NTOKW*192;        // 26,542,080
  const size_t REG_B = (size_t)NTOKW*576;        // 79,626,240
  const size_t W_QT  = (size_t)2*576*192;
  const size_t W_PT  = (size_t)2*192*192;
  const size_t W_1T  = (size_t)2*768*192;
  const size_t W_2T  = (size_t)2*192*768;
  const size_t TOT_SH = REG_A + REG_B + W_QT + W_PT + W_1T + W_2T;
  const size_t NEEDED = TOT_SH*2 + (size_t)NTOK*192*4;   // + fp32 xmidf
  if (ws_size < NEEDED) return;   // diagnostic guard: fail validation, not fault

  unsigned short* ws16 = (unsigned short*)d_ws;
  size_t off = 0;
  unsigned short* regA = ws16 + off; off += REG_A;   // xw / attn-out / xmidb
  unsigned short* regB = ws16 + off; off += REG_B;   // qkv-out / proj-out / mlp-out
  unsigned short* wqt  = ws16 + off; off += W_QT;
  unsigned short* wpt  = ws16 + off; off += W_PT;
  unsigned short* w1t  = ws16 + off; off += W_1T;
  unsigned short* w2t  = ws16 + off; off += W_2T;
  float* xmidf = (float*)(ws16 + off);

  // pre-transpose weights to [N][K] bf16
  for (int dep=0; dep<2; dep++){
    transp<<<(192*576+255)/256,256,0,stream>>>(qkvw + (size_t)dep*192*576,
                                               wqt + (size_t)dep*576*192, 192, 576);
    transp<<<(192*192+255)/256,256,0,stream>>>(projw + (size_t)dep*192*192,
                                               wpt + (size_t)dep*192*192, 192, 192);
    transp<<<(192*768+255)/256,256,0,stream>>>(w1 + (size_t)dep*192*768,
                                               w1t + (size_t)dep*768*192, 192, 768);
    transp<<<(768*192+255)/256,256,0,stream>>>(w2 + (size_t)dep*768*192,
                                               w2t + (size_t)dep*192*768, 768, 192);
  }

  for (int dep=0; dep<2; dep++){
    int roll = dep;
    const float* xs = (dep==0) ? x_in : outp;   // d_out holds block-0 trunk
    float* xout = outp;

    gather_win<<<NTOKW*24/256, 256, 0, stream>>>(xs, regA, roll);

    dim3 g1(NTOKW/128, 576/64);
    gemm_bf16<<<g1, 256, 0, stream>>>(regA, wqt + (size_t)dep*576*192,
                                      qkvbias + dep*576, regB, NTOKW, 576, 192);

    attn_win<<<960*6, 576, 0, stream>>>(regB, btab + (size_t)dep*3312*384, regA, roll);

    dim3 g2(NTOKW/128, 192/64);
    gemm_bf16<<<g2, 256, 0, stream>>>(regA, wpt + (size_t)dep*192*192,
                                      projbias + dep*192, regB, NTOKW, 192, 192);

    unwin_ln<<<NTOK/4, 256, 0, stream>>>(regB, xs, n1g + dep*192, n1b + dep*192,
                                         xmidf, regA, roll);

    mlp_fused<<<(NTOK+63)/64, 256, 0, stream>>>(regA, w1t + (size_t)dep*768*192,
                                                b1 + dep*768, w2t + (size_t)dep*192*768,
                                                b2 + dep*192, regB, NTOK);

    add_ln<<<NTOK/4, 256, 0, stream>>>(regB, xmidf, n2g + dep*192, n2b + dep*192, xout);
  }
}

// Round 4
// 1296.833 us; speedup vs baseline: 1.3404x; 1.3404x over previous
//
#include <hip/hip_runtime.h>
#include <math.h>

#define NTOK   131040   // 8*91*180
#define NTOKW  138240   // 15*64*144

typedef __attribute__((ext_vector_type(8))) short bf16x8;
typedef __attribute__((ext_vector_type(8))) unsigned short u16x8;
typedef __attribute__((ext_vector_type(4))) float f32x4;

__device__ __forceinline__ float b2f(unsigned short u){
  union { unsigned u; float f; } v; v.u = ((unsigned)u) << 16; return v.f;
}
__device__ __forceinline__ unsigned short f2b(float f){
  union { float f; unsigned u; } v; v.f = f;
  unsigned r = v.u + 0x7FFFu + ((v.u >> 16) & 1u);
  return (unsigned short)(r >> 16);
}

// transpose-cast: dst[n][k] = (bf16)src[k][n]   (dst is [N][K])
__global__ __launch_bounds__(256) void transp(const float* __restrict__ src,
                                              unsigned short* __restrict__ dst,
                                              int K, int N){
  int i = blockIdx.x*256 + threadIdx.x;
  if (i < K*N){
    int n = i / K, k = i % K;
    dst[i] = f2b(src[(size_t)k*N + n]);
  }
}

// precompute bias+mask table: bw[tw][head][i][j] bf16, read-order layout
__global__ __launch_bounds__(256) void bias_pre(
    const float* __restrict__ btab,     // [3312][64][6] depth-sliced
    unsigned short* __restrict__ bw,    // [64*6][144*144]
    int roll)
{
  int gid = blockIdx.x*256 + threadIdx.x;   // < 64*6*20736
  int pair = gid / 20736;        // tw*6+head
  int rem  = gid % 20736;
  int i = rem / 144, j = rem % 144;
  int tw = pair / 6, head = pair % 6;
  int ia = i/72, ib = (i%72)/12, ic = i%12;
  int ja = j/72, jb = (j%72)/12, jc = j%12;
  int idx = (ia + 2*ja)*828 + (ib + 6*jb)*23 + (ic - jc + 11);
  float v = btab[(size_t)idx*384 + tw*6 + head];
  if (roll){
    int nz = tw >> 4, nh = tw & 15;
    int zi = nz*2+ia, hi = nh*6+ib, zj = nz*2+ja, hj = nh*6+jb;
    int ri = 3*((zi<6)?0:((zi<7)?1:2)) + ((hi<90)?0:((hi<93)?1:2));
    int rj = 3*((zj<6)?0:((zj<7)?1:2)) + ((hj<90)?0:((hj<93)?1:2));
    if (ri != rj) v -= 100.0f;
  }
  bw[gid] = f2b(v);
}

// window-partition gather (+pad +roll), fp32 -> bf16
__global__ __launch_bounds__(256) void gather_win(const float* __restrict__ x,
                                                  unsigned short* __restrict__ xw,
                                                  int roll){
  int gid = blockIdx.x*256 + threadIdx.x;
  int row = gid / 24;
  int dp  = gid % 24;
  int tok = row % 144;
  int wt  = row / 144;          // w*64+tw
  int tw  = wt & 63;
  int w   = wt >> 6;
  int nz = tw >> 4, nh = tw & 15;
  int wz = tok / 72; int rem = tok % 72; int wh = rem / 12; int ww = rem % 12;
  int z = nz*2 + wz, h = nh*6 + wh, wc = w*12 + ww;
  if (roll){ z = (z+1)&7; h = (h+3)%96; wc = (wc+6)%180; }
  int d0 = dp*8;
  u16x8 o;
  if (h < 91){
    const float* s = x + ((size_t)((z*91 + h)*180 + wc))*192 + d0;
    #pragma unroll
    for (int i=0;i<8;i++) o[i] = f2b(s[i]);
  } else {
    #pragma unroll
    for (int i=0;i<8;i++) o[i] = 0;
  }
  *(u16x8*)(xw + (size_t)row*192 + d0) = o;
}

// bf16 MFMA GEMM: C[MxN] = A[MxK] @ Bt[NxK]^T + bias   (K multiple of 32)
__global__ __launch_bounds__(256) void gemm_bf16(
    const unsigned short* __restrict__ A,
    const unsigned short* __restrict__ Bt,
    const float* __restrict__ bias,
    unsigned short* __restrict__ C,
    int M, int N, int K)
{
  __shared__ unsigned short As[128][40];
  __shared__ unsigned short Bst[64][40];   // [col][k]
  int m0 = blockIdx.x * 128;
  int n0 = blockIdx.y * 64;
  int t = threadIdx.x;
  int lane = t & 63, wid = t >> 6;
  int wm = wid >> 1, wn = wid & 1;
  int lg = lane >> 4, lr = lane & 15;
  f32x4 acc[4][2];
  #pragma unroll
  for (int a=0;a<4;a++)
    #pragma unroll
    for (int b=0;b<2;b++) acc[a][b] = (f32x4){0.f,0.f,0.f,0.f};

  int arow = t >> 1, ac0 = (t & 1) * 16;
  int bcol = t >> 2, bk = (t & 3) * 8;

  for (int k0 = 0; k0 < K; k0 += 32){
    {
      int gr = m0 + arow;
      u16x8 v0, v1;
      if (gr < M){
        const unsigned short* src = A + (size_t)gr*K + k0 + ac0;
        v0 = *(const u16x8*)src;
        v1 = *(const u16x8*)(src+8);
      } else {
        #pragma unroll
        for (int i=0;i<8;i++){ v0[i]=0; v1[i]=0; }
      }
      *(u16x8*)&As[arow][ac0]   = v0;
      *(u16x8*)&As[arow][ac0+8] = v1;
    }
    {
      u16x8 vb = *(const u16x8*)(Bt + (size_t)(n0 + bcol)*K + k0 + bk);
      *(u16x8*)&Bst[bcol][bk] = vb;
    }
    __syncthreads();
    #pragma unroll
    for (int fn=0; fn<2; fn++){
      bf16x8 bfr = *(const bf16x8*)&Bst[wn*32 + fn*16 + lr][lg*8];
      #pragma unroll
      for (int fm=0; fm<4; fm++){
        bf16x8 afr = *(const bf16x8*)&As[wm*64 + fm*16 + lr][lg*8];
        acc[fm][fn] = __builtin_amdgcn_mfma_f32_16x16x32_bf16(afr, bfr, acc[fm][fn], 0,0,0);
      }
    }
    __syncthreads();
  }
  #pragma unroll
  for (int fm=0; fm<4; fm++){
    #pragma unroll
    for (int fn=0; fn<2; fn++){
      #pragma unroll
      for (int r=0;r<4;r++){
        int rowg = m0 + wm*64 + fm*16 + lg*4 + r;
        int colg = n0 + wn*32 + fn*16 + lr;
        if (rowg < M){
          C[(size_t)rowg*N + colg] = f2b(acc[fm][fn][r] + bias[colg]);
        }
      }
    }
  }
}

// fused windowed attention: one block per (window-pair, head). 9 waves.
__global__ __launch_bounds__(576) void attn_win(
    const unsigned short* __restrict__ qkv,   // [NTOKW][576]
    const unsigned short* __restrict__ bw,    // [64*6][144*144] precomputed bias+mask
    unsigned short* __restrict__ outp)        // [NTOKW][192]
{
  __shared__ unsigned short Qs[144][32];
  __shared__ unsigned short Ks[144][40];
  __shared__ unsigned short Vst[32][168];
  __shared__ unsigned short Ps[144][168];

  int b = blockIdx.x;
  int head = b % 6;
  int wt = b / 6;          // w*64+tw
  int tw = wt & 63;
  int t = threadIdx.x;
  int lane = t & 63;
  int wv = t >> 6;         // 0..8
  int lg = lane >> 4, lr = lane & 15;

  {
    int tok = t >> 2, c0 = (t & 3)*8;
    size_t base = ((size_t)wt*144 + tok)*576 + head*32 + c0;
    u16x8 qv = *(const u16x8*)(qkv + base);
    u16x8 kv = *(const u16x8*)(qkv + base + 192);
    u16x8 vv = *(const u16x8*)(qkv + base + 384);
    u16x8 qs;
    #pragma unroll
    for (int i=0;i<8;i++) qs[i] = f2b(b2f(qv[i]) * 0.17677669529663687f);
    *(u16x8*)&Qs[tok][c0] = qs;
    *(u16x8*)&Ks[tok][c0] = kv;
    #pragma unroll
    for (int i=0;i<8;i++) Vst[c0+i][tok] = vv[i];
  }
  if (t < 512) Vst[t >> 4][144 + (t & 15)] = 0;
  __syncthreads();

  float s[9][4];
  {
    bf16x8 a = *(const bf16x8*)&Qs[wv*16 + lr][lg*8];
    #pragma unroll
    for (int ct=0; ct<9; ct++){
      bf16x8 bb = *(const bf16x8*)&Ks[ct*16 + lr][lg*8];
      f32x4 d = {0.f,0.f,0.f,0.f};
      d = __builtin_amdgcn_mfma_f32_16x16x32_bf16(a, bb, d, 0,0,0);
      s[ct][0]=d[0]; s[ct][1]=d[1]; s[ct][2]=d[2]; s[ct][3]=d[3];
    }
  }

  // precomputed bias+mask: bw[(tw*6+head)][i*144 + j]
  {
    const unsigned short* bp = bw + (size_t)(tw*6 + head)*20736;
    int i0 = wv*16 + lg*4;
    #pragma unroll
    for (int ct=0; ct<9; ct++){
      int j = ct*16 + lr;
      #pragma unroll
      for (int r=0;r<4;r++)
        s[ct][r] += b2f(bp[(i0 + r)*144 + j]);
    }
  }

  float mx[4] = {-1e30f,-1e30f,-1e30f,-1e30f};
  #pragma unroll
  for (int ct=0; ct<9; ct++)
    #pragma unroll
    for (int r=0;r<4;r++) mx[r] = fmaxf(mx[r], s[ct][r]);
  #pragma unroll
  for (int off=1; off<16; off<<=1)
    #pragma unroll
    for (int r=0;r<4;r++) mx[r] = fmaxf(mx[r], __shfl_xor(mx[r], off));
  float sm[4] = {0.f,0.f,0.f,0.f};
  #pragma unroll
  for (int ct=0; ct<9; ct++)
    #pragma unroll
    for (int r=0;r<4;r++){ s[ct][r] = __expf(s[ct][r] - mx[r]); sm[r] += s[ct][r]; }
  #pragma unroll
  for (int off=1; off<16; off<<=1)
    #pragma unroll
    for (int r=0;r<4;r++) sm[r] += __shfl_xor(sm[r], off);
  float inv[4];
  #pragma unroll
  for (int r=0;r<4;r++) inv[r] = 1.0f / sm[r];
  #pragma unroll
  for (int ct=0; ct<9; ct++)
    #pragma unroll
    for (int r=0;r<4;r++)
      Ps[wv*16 + lg*4 + r][ct*16 + lr] = f2b(s[ct][r] * inv[r]);
  #pragma unroll
  for (int r=0;r<4;r++) Ps[wv*16 + lg*4 + r][144 + lr] = 0;
  __syncthreads();

  #pragma unroll
  for (int ct2=0; ct2<2; ct2++){
    f32x4 o = {0.f,0.f,0.f,0.f};
    #pragma unroll
    for (int kt=0; kt<5; kt++){
      bf16x8 a  = *(const bf16x8*)&Ps[wv*16 + lr][kt*32 + lg*8];
      bf16x8 bb = *(const bf16x8*)&Vst[ct2*16 + lr][kt*32 + lg*8];
      o = __builtin_amdgcn_mfma_f32_16x16x32_bf16(a, bb, o, 0,0,0);
    }
    size_t rb = ((size_t)wt*144 + wv*16 + lg*4)*192 + head*32 + ct2*16 + lr;
    #pragma unroll
    for (int r=0;r<4;r++) outp[rb + (size_t)r*192] = f2b(o[r]);
  }
}

// un-window (+unroll +crop) + LN + residual; writes fp32 trunk + bf16 copy
__global__ __launch_bounds__(256) void unwin_ln(
  const unsigned short* __restrict__ ywin,
  const float* __restrict__ xsrc,
  const float* __restrict__ g, const float* __restrict__ bb,
  float* __restrict__ outf, unsigned short* __restrict__ outb, int roll)
{
  int tok = blockIdx.x*4 + (threadIdx.x>>6);
  if (tok >= NTOK) return;
  int lane = threadIdx.x & 63;
  int z = tok / (91*180);
  int rem = tok % (91*180);
  int h = rem / 180, wc = rem % 180;
  int zz=z, hh=h, ww=wc;
  if (roll){ zz = (z+7)&7; hh = (h+93)%96; ww = (wc+174)%180; }
  int nz = zz>>1, wz = zz&1;
  int nh = hh/6,  wh = hh%6;
  int nw = ww/12, w2 = ww%12;
  size_t row = ((size_t)(nw*64 + nz*16 + nh))*144 + wz*72 + wh*12 + w2;
  const unsigned short* yr = ywin + row*192;
  float v[3]; float s=0.f, ss=0.f;
  #pragma unroll
  for (int i=0;i<3;i++){ v[i] = b2f(yr[lane + i*64]); s += v[i]; ss += v[i]*v[i]; }
  #pragma unroll
  for (int off=32; off>=1; off>>=1){ s += __shfl_xor(s, off); ss += __shfl_xor(ss, off); }
  float mean = s * (1.0f/192.0f);
  float var = ss * (1.0f/192.0f) - mean*mean;
  float rinv = rsqrtf(var + 1e-5f);
  size_t tb = (size_t)tok*192;
  #pragma unroll
  for (int i=0;i<3;i++){
    int d = lane + i*64;
    float o = xsrc[tb + d] + ((v[i]-mean)*rinv*g[d] + bb[d]);
    outf[tb+d] = o;
    outb[tb+d] = f2b(o);
  }
}

// fused MLP: C = gelu(A @ W1 + b1) @ W2 + b2, hidden chunked by 32
__global__ __launch_bounds__(256) void mlp_fused(
    const unsigned short* __restrict__ A,    // [M][192]
    const unsigned short* __restrict__ W1t,  // [768][192]
    const float* __restrict__ b1,            // [768]
    const unsigned short* __restrict__ W2t,  // [192][768]
    const float* __restrict__ b2,            // [192]
    unsigned short* __restrict__ C,          // [M][192]
    int M)
{
  __shared__ unsigned short As [64][200];
  __shared__ unsigned short W1s[32][200];
  __shared__ unsigned short W2s[192][40];
  __shared__ unsigned short Hs [64][40];
  int m0 = blockIdx.x*64;
  int t = threadIdx.x; int lane = t & 63; int w = t >> 6;
  int lg = lane >> 4, lr = lane & 15;

  #pragma unroll
  for (int i=0;i<6;i++){
    int idx = t + i*256;            // 0..1535
    int r = idx / 24, c0 = (idx % 24)*8;
    int gr = m0 + r;
    u16x8 v;
    if (gr < M){
      v = *(const u16x8*)(A + (size_t)gr*192 + c0);
    } else {
      for (int j=0;j<8;j++) v[j]=0;
    }
    *(u16x8*)&As[r][c0] = v;
  }

  f32x4 acc[4][3];
  #pragma unroll
  for (int a=0;a<4;a++)
    #pragma unroll
    for (int b=0;b<3;b++) acc[a][b] = (f32x4){0.f,0.f,0.f,0.f};

  int colt = w & 1, rh = w >> 1;

  for (int hc = 0; hc < 768; hc += 32){
    #pragma unroll
    for (int i=0;i<3;i++){
      int idx = t + i*256;          // 0..767
      int r = idx / 24, c0 = (idx % 24)*8;
      *(u16x8*)&W1s[r][c0] = *(const u16x8*)(W1t + (size_t)(hc + r)*192 + c0);
    }
    #pragma unroll
    for (int i=0;i<3;i++){
      int idx = t + i*256;          // 0..767
      int r = idx / 4, c0 = (idx & 3)*8;
      *(u16x8*)&W2s[r][c0] = *(const u16x8*)(W2t + (size_t)r*768 + hc + c0);
    }
    __syncthreads();

    f32x4 h[2];
    h[0] = (f32x4){0.f,0.f,0.f,0.f};
    h[1] = (f32x4){0.f,0.f,0.f,0.f};
    #pragma unroll
    for (int ks=0; ks<6; ks++){
      bf16x8 bfr = *(const bf16x8*)&W1s[colt*16 + lr][ks*32 + lg*8];
      #pragma unroll
      for (int fm=0; fm<2; fm++){
        bf16x8 afr = *(const bf16x8*)&As[rh*32 + fm*16 + lr][ks*32 + lg*8];
        h[fm] = __builtin_amdgcn_mfma_f32_16x16x32_bf16(afr, bfr, h[fm], 0,0,0);
      }
    }
    #pragma unroll
    for (int fm=0; fm<2; fm++)
      #pragma unroll
      for (int r=0;r<4;r++){
        float v = h[fm][r] + b1[hc + colt*16 + lr];
        v = 0.5f*v*(1.0f + erff(v*0.70710678118654752f));
        Hs[rh*32 + fm*16 + lg*4 + r][colt*16 + lr] = f2b(v);
      }
    __syncthreads();

    #pragma unroll
    for (int fn=0; fn<3; fn++){
      bf16x8 bfr = *(const bf16x8*)&W2s[w*48 + fn*16 + lr][lg*8];
      #pragma unroll
      for (int fm=0; fm<4; fm++){
        bf16x8 afr = *(const bf16x8*)&Hs[fm*16 + lr][lg*8];
        acc[fm][fn] = __builtin_amdgcn_mfma_f32_16x16x32_bf16(afr, bfr, acc[fm][fn], 0,0,0);
      }
    }
    __syncthreads();
  }

  #pragma unroll
  for (int fm=0; fm<4; fm++)
    #pragma unroll
    for (int fn=0; fn<3; fn++)
      #pragma unroll
      for (int r=0;r<4;r++){
        int rowg = m0 + fm*16 + lg*4 + r;
        int colg = w*48 + fn*16 + lr;
        if (rowg < M) C[(size_t)rowg*192 + colg] = f2b(acc[fm][fn][r] + b2[colg]);
      }
}

// out = xmid + LN(ymlp)
__global__ __launch_bounds__(256) void add_ln(
  const unsigned short* __restrict__ ymlp,
  const float* __restrict__ xmid,
  const float* __restrict__ g, const float* __restrict__ bb,
  float* __restrict__ outf)
{
  int tok = blockIdx.x*4 + (threadIdx.x>>6);
  if (tok >= NTOK) return;
  int lane = threadIdx.x & 63;
  const unsigned short* yr = ymlp + (size_t)tok*192;
  float v[3]; float s=0.f, ss=0.f;
  #pragma unroll
  for (int i=0;i<3;i++){ v[i] = b2f(yr[lane + i*64]); s += v[i]; ss += v[i]*v[i]; }
  #pragma unroll
  for (int off=32; off>=1; off>>=1){ s += __shfl_xor(s, off); ss += __shfl_xor(ss, off); }
  float mean = s * (1.0f/192.0f);
  float var = ss * (1.0f/192.0f) - mean*mean;
  float rinv = rsqrtf(var + 1e-5f);
  size_t tb = (size_t)tok*192;
  #pragma unroll
  for (int i=0;i<3;i++){
    int d = lane + i*64;
    outf[tb+d] = xmid[tb + d] + ((v[i]-mean)*rinv*g[d] + bb[d]);
  }
}

extern "C" void kernel_launch(void* const* d_in, const int* in_sizes, int n_in,
                              void* d_out, int out_size, void* d_ws, size_t ws_size,
                              hipStream_t stream)
{
  const float* x_in    = (const float*)d_in[0];
  const float* qkvw    = (const float*)d_in[1];
  const float* qkvbias = (const float*)d_in[2];
  const float* projw   = (const float*)d_in[3];
  const float* projbias= (const float*)d_in[4];
  const float* btab    = (const float*)d_in[5];
  const float* n1g = (const float*)d_in[6];
  const float* n1b = (const float*)d_in[7];
  const float* n2g = (const float*)d_in[8];
  const float* n2b = (const float*)d_in[9];
  const float* w1  = (const float*)d_in[10];
  const float* b1  = (const float*)d_in[11];
  const float* w2  = (const float*)d_in[12];
  const float* b2  = (const float*)d_in[13];
  float* outp = (float*)d_out;

  // workspace layout (shorts)
  const size_t REG_A = (size_t)NTOKW*192;        // 26,542,080
  const size_t REG_B = (size_t)NTOKW*576;        // 79,626,240
  const size_t W_QT  = (size_t)2*576*192;
  const size_t W_PT  = (size_t)2*192*192;
  const size_t W_1T  = (size_t)2*768*192;
  const size_t W_2T  = (size_t)2*192*768;
  const size_t TOT_SH = REG_A + REG_B + W_QT + W_PT + W_1T + W_2T;
  const size_t NEEDED = TOT_SH*2 + (size_t)NTOK*192*4;   // + fp32 xmidf (bw aliases it)
  if (ws_size < NEEDED) return;   // guard

  unsigned short* ws16 = (unsigned short*)d_ws;
  size_t off = 0;
  unsigned short* regA = ws16 + off; off += REG_A;   // xw / attn-out / xmidb
  unsigned short* regB = ws16 + off; off += REG_B;   // qkv-out / proj-out / mlp-out
  unsigned short* wqt  = ws16 + off; off += W_QT;
  unsigned short* wpt  = ws16 + off; off += W_PT;
  unsigned short* w1t  = ws16 + off; off += W_1T;
  unsigned short* w2t  = ws16 + off; off += W_2T;
  float* xmidf = (float*)(ws16 + off);
  unsigned short* bw = (unsigned short*)xmidf;   // alias: bias table dead before unwin_ln writes

  // pre-transpose weights to [N][K] bf16
  for (int dep=0; dep<2; dep++){
    transp<<<(192*576+255)/256,256,0,stream>>>(qkvw + (size_t)dep*192*576,
                                               wqt + (size_t)dep*576*192, 192, 576);
    transp<<<(192*192+255)/256,256,0,stream>>>(projw + (size_t)dep*192*192,
                                               wpt + (size_t)dep*192*192, 192, 192);
    transp<<<(192*768+255)/256,256,0,stream>>>(w1 + (size_t)dep*192*768,
                                               w1t + (size_t)dep*768*192, 192, 768);
    transp<<<(768*192+255)/256,256,0,stream>>>(w2 + (size_t)dep*768*192,
                                               w2t + (size_t)dep*192*768, 768, 192);
  }

  for (int dep=0; dep<2; dep++){
    int roll = dep;
    const float* xs = (dep==0) ? x_in : outp;   // d_out holds block-0 trunk
    float* xout = outp;

    gather_win<<<NTOKW*24/256, 256, 0, stream>>>(xs, regA, roll);

    dim3 g1(NTOKW/128, 576/64);
    gemm_bf16<<<g1, 256, 0, stream>>>(regA, wqt + (size_t)dep*576*192,
                                      qkvbias + dep*576, regB, NTOKW, 576, 192);

    bias_pre<<<(64*6*20736)/256, 256, 0, stream>>>(btab + (size_t)dep*3312*384, bw, roll);

    attn_win<<<960*6, 576, 0, stream>>>(regB, bw, regA);

    dim3 g2(NTOKW/128, 192/64);
    gemm_bf16<<<g2, 256, 0, stream>>>(regA, wpt + (size_t)dep*192*192,
                                      projbias + dep*192, regB, NTOKW, 192, 192);

    unwin_ln<<<NTOK/4, 256, 0, stream>>>(regB, xs, n1g + dep*192, n1b + dep*192,
                                         xmidf, regA, roll);

    mlp_fused<<<(NTOK+63)/64, 256, 0, stream>>>(regA, w1t + (size_t)dep*768*192,
                                                b1 + dep*768, w2t + (size_t)dep*192*768,
                                                b2 + dep*192, regB, NTOK);

    add_ln<<<NTOK/4, 256, 0, stream>>>(regB, xmidf, n2g + dep*192, n2b + dep*192, xout);
  }
}

// Round 5
// 1255.226 us; speedup vs baseline: 1.3848x; 1.0331x over previous
//
#include <hip/hip_runtime.h>
#include <math.h>

#define NTOK   131040   // 8*91*180
#define NTOKW  138240   // 15*64*144

typedef __attribute__((ext_vector_type(8))) short bf16x8;
typedef __attribute__((ext_vector_type(8))) unsigned short u16x8;
typedef __attribute__((ext_vector_type(4))) float f32x4;

__device__ __forceinline__ float b2f(unsigned short u){
  union { unsigned u; float f; } v; v.u = ((unsigned)u) << 16; return v.f;
}
__device__ __forceinline__ unsigned short f2b(float f){
  union { float f; unsigned u; } v; v.f = f;
  unsigned r = v.u + 0x7FFFu + ((v.u >> 16) & 1u);
  return (unsigned short)(r >> 16);
}
__device__ __forceinline__ float gelu_tanh(float x){
  // 0.5x(1+tanh(0.79788456(x+0.044715x^3))), max |err vs exact erf-GELU| ~3e-4
  float t = 0.79788456080286536f * (x + 0.044715f * x * x * x);
  float e = __expf(2.0f * t);           // +inf ok, 0 ok
  float th = 1.0f - 2.0f / (e + 1.0f);
  return 0.5f * x * (1.0f + th);
}

// transpose-cast: dst[n][k] = (bf16)src[k][n]   (dst is [N][K])
__global__ __launch_bounds__(256) void transp(const float* __restrict__ src,
                                              unsigned short* __restrict__ dst,
                                              int K, int N){
  int i = blockIdx.x*256 + threadIdx.x;
  if (i < K*N){
    int n = i / K, k = i % K;
    dst[i] = f2b(src[(size_t)k*N + n]);
  }
}

// precompute bias+mask table: bw[tw][head][i][j] bf16, read-order layout
__global__ __launch_bounds__(256) void bias_pre(
    const float* __restrict__ btab,     // [3312][64][6] depth-sliced
    unsigned short* __restrict__ bw,    // [64*6][144*144]
    int roll)
{
  int gid = blockIdx.x*256 + threadIdx.x;   // < 64*6*20736
  int pair = gid / 20736;        // tw*6+head
  int rem  = gid % 20736;
  int i = rem / 144, j = rem % 144;
  int tw = pair / 6, head = pair % 6;
  int ia = i/72, ib = (i%72)/12, ic = i%12;
  int ja = j/72, jb = (j%72)/12, jc = j%12;
  int idx = (ia + 2*ja)*828 + (ib + 6*jb)*23 + (ic - jc + 11);
  float v = btab[(size_t)idx*384 + tw*6 + head];
  if (roll){
    int nz = tw >> 4, nh = tw & 15;
    int zi = nz*2+ia, hi = nh*6+ib, zj = nz*2+ja, hj = nh*6+jb;
    int ri = 3*((zi<6)?0:((zi<7)?1:2)) + ((hi<90)?0:((hi<93)?1:2));
    int rj = 3*((zj<6)?0:((zj<7)?1:2)) + ((hj<90)?0:((hj<93)?1:2));
    if (ri != rj) v -= 100.0f;
  }
  bw[gid] = f2b(v);
}

// window-partition gather (+pad +roll), fp32 -> bf16
__global__ __launch_bounds__(256) void gather_win(const float* __restrict__ x,
                                                  unsigned short* __restrict__ xw,
                                                  int roll){
  int gid = blockIdx.x*256 + threadIdx.x;
  int row = gid / 24;
  int dp  = gid % 24;
  int tok = row % 144;
  int wt  = row / 144;          // w*64+tw
  int tw  = wt & 63;
  int w   = wt >> 6;
  int nz = tw >> 4, nh = tw & 15;
  int wz = tok / 72; int rem = tok % 72; int wh = rem / 12; int ww = rem % 12;
  int z = nz*2 + wz, h = nh*6 + wh, wc = w*12 + ww;
  if (roll){ z = (z+1)&7; h = (h+3)%96; wc = (wc+6)%180; }
  int d0 = dp*8;
  u16x8 o;
  if (h < 91){
    const float* s = x + ((size_t)((z*91 + h)*180 + wc))*192 + d0;
    #pragma unroll
    for (int i=0;i<8;i++) o[i] = f2b(s[i]);
  } else {
    #pragma unroll
    for (int i=0;i<8;i++) o[i] = 0;
  }
  *(u16x8*)(xw + (size_t)row*192 + d0) = o;
}

// bf16 MFMA GEMM: C[MxN] = A[MxK] @ Bt[NxK]^T + bias   (K multiple of 32)
__global__ __launch_bounds__(256) void gemm_bf16(
    const unsigned short* __restrict__ A,
    const unsigned short* __restrict__ Bt,
    const float* __restrict__ bias,
    unsigned short* __restrict__ C,
    int M, int N, int K)
{
  __shared__ unsigned short As[128][40];
  __shared__ unsigned short Bst[64][40];   // [col][k]
  int m0 = blockIdx.x * 128;
  int n0 = blockIdx.y * 64;
  int t = threadIdx.x;
  int lane = t & 63, wid = t >> 6;
  int wm = wid >> 1, wn = wid & 1;
  int lg = lane >> 4, lr = lane & 15;
  f32x4 acc[4][2];
  #pragma unroll
  for (int a=0;a<4;a++)
    #pragma unroll
    for (int b=0;b<2;b++) acc[a][b] = (f32x4){0.f,0.f,0.f,0.f};

  int arow = t >> 1, ac0 = (t & 1) * 16;
  int bcol = t >> 2, bk = (t & 3) * 8;

  for (int k0 = 0; k0 < K; k0 += 32){
    {
      int gr = m0 + arow;
      u16x8 v0, v1;
      if (gr < M){
        const unsigned short* src = A + (size_t)gr*K + k0 + ac0;
        v0 = *(const u16x8*)src;
        v1 = *(const u16x8*)(src+8);
      } else {
        #pragma unroll
        for (int i=0;i<8;i++){ v0[i]=0; v1[i]=0; }
      }
      *(u16x8*)&As[arow][ac0]   = v0;
      *(u16x8*)&As[arow][ac0+8] = v1;
    }
    {
      u16x8 vb = *(const u16x8*)(Bt + (size_t)(n0 + bcol)*K + k0 + bk);
      *(u16x8*)&Bst[bcol][bk] = vb;
    }
    __syncthreads();
    #pragma unroll
    for (int fn=0; fn<2; fn++){
      bf16x8 bfr = *(const bf16x8*)&Bst[wn*32 + fn*16 + lr][lg*8];
      #pragma unroll
      for (int fm=0; fm<4; fm++){
        bf16x8 afr = *(const bf16x8*)&As[wm*64 + fm*16 + lr][lg*8];
        acc[fm][fn] = __builtin_amdgcn_mfma_f32_16x16x32_bf16(afr, bfr, acc[fm][fn], 0,0,0);
      }
    }
    __syncthreads();
  }
  #pragma unroll
  for (int fm=0; fm<4; fm++){
    #pragma unroll
    for (int fn=0; fn<2; fn++){
      #pragma unroll
      for (int r=0;r<4;r++){
        int rowg = m0 + wm*64 + fm*16 + lg*4 + r;
        int colg = n0 + wn*32 + fn*16 + lr;
        if (rowg < M){
          C[(size_t)rowg*N + colg] = f2b(acc[fm][fn][r] + bias[colg]);
        }
      }
    }
  }
}

// fused windowed attention: one block per (window-pair, head). 9 waves.
__global__ __launch_bounds__(576) void attn_win(
    const unsigned short* __restrict__ qkv,   // [NTOKW][576]
    const unsigned short* __restrict__ bw,    // [64*6][144*144] precomputed bias+mask
    unsigned short* __restrict__ outp)        // [NTOKW][192]
{
  __shared__ unsigned short Qs[144][32];
  __shared__ unsigned short Ks[144][40];
  __shared__ unsigned short Vst[32][168];
  __shared__ unsigned short Ps[144][168];

  int b = blockIdx.x;
  int head = b % 6;
  int wt = b / 6;          // w*64+tw
  int tw = wt & 63;
  int t = threadIdx.x;
  int lane = t & 63;
  int wv = t >> 6;         // 0..8
  int lg = lane >> 4, lr = lane & 15;

  {
    int tok = t >> 2, c0 = (t & 3)*8;
    size_t base = ((size_t)wt*144 + tok)*576 + head*32 + c0;
    u16x8 qv = *(const u16x8*)(qkv + base);
    u16x8 kv = *(const u16x8*)(qkv + base + 192);
    u16x8 vv = *(const u16x8*)(qkv + base + 384);
    u16x8 qs;
    #pragma unroll
    for (int i=0;i<8;i++) qs[i] = f2b(b2f(qv[i]) * 0.17677669529663687f);
    *(u16x8*)&Qs[tok][c0] = qs;
    *(u16x8*)&Ks[tok][c0] = kv;
    #pragma unroll
    for (int i=0;i<8;i++) Vst[c0+i][tok] = vv[i];
  }
  if (t < 512) Vst[t >> 4][144 + (t & 15)] = 0;
  __syncthreads();

  float s[9][4];
  {
    bf16x8 a = *(const bf16x8*)&Qs[wv*16 + lr][lg*8];
    #pragma unroll
    for (int ct=0; ct<9; ct++){
      bf16x8 bb = *(const bf16x8*)&Ks[ct*16 + lr][lg*8];
      f32x4 d = {0.f,0.f,0.f,0.f};
      d = __builtin_amdgcn_mfma_f32_16x16x32_bf16(a, bb, d, 0,0,0);
      s[ct][0]=d[0]; s[ct][1]=d[1]; s[ct][2]=d[2]; s[ct][3]=d[3];
    }
  }

  // precomputed bias+mask: bw[(tw*6+head)][i*144 + j]
  {
    const unsigned short* bp = bw + (size_t)(tw*6 + head)*20736;
    int i0 = wv*16 + lg*4;
    #pragma unroll
    for (int ct=0; ct<9; ct++){
      int j = ct*16 + lr;
      #pragma unroll
      for (int r=0;r<4;r++)
        s[ct][r] += b2f(bp[(i0 + r)*144 + j]);
    }
  }

  float mx[4] = {-1e30f,-1e30f,-1e30f,-1e30f};
  #pragma unroll
  for (int ct=0; ct<9; ct++)
    #pragma unroll
    for (int r=0;r<4;r++) mx[r] = fmaxf(mx[r], s[ct][r]);
  #pragma unroll
  for (int off=1; off<16; off<<=1)
    #pragma unroll
    for (int r=0;r<4;r++) mx[r] = fmaxf(mx[r], __shfl_xor(mx[r], off));
  float sm[4] = {0.f,0.f,0.f,0.f};
  #pragma unroll
  for (int ct=0; ct<9; ct++)
    #pragma unroll
    for (int r=0;r<4;r++){ s[ct][r] = __expf(s[ct][r] - mx[r]); sm[r] += s[ct][r]; }
  #pragma unroll
  for (int off=1; off<16; off<<=1)
    #pragma unroll
    for (int r=0;r<4;r++) sm[r] += __shfl_xor(sm[r], off);
  float inv[4];
  #pragma unroll
  for (int r=0;r<4;r++) inv[r] = 1.0f / sm[r];
  #pragma unroll
  for (int ct=0; ct<9; ct++)
    #pragma unroll
    for (int r=0;r<4;r++)
      Ps[wv*16 + lg*4 + r][ct*16 + lr] = f2b(s[ct][r] * inv[r]);
  #pragma unroll
  for (int r=0;r<4;r++) Ps[wv*16 + lg*4 + r][144 + lr] = 0;
  __syncthreads();

  #pragma unroll
  for (int ct2=0; ct2<2; ct2++){
    f32x4 o = {0.f,0.f,0.f,0.f};
    #pragma unroll
    for (int kt=0; kt<5; kt++){
      bf16x8 a  = *(const bf16x8*)&Ps[wv*16 + lr][kt*32 + lg*8];
      bf16x8 bb = *(const bf16x8*)&Vst[ct2*16 + lr][kt*32 + lg*8];
      o = __builtin_amdgcn_mfma_f32_16x16x32_bf16(a, bb, o, 0,0,0);
    }
    size_t rb = ((size_t)wt*144 + wv*16 + lg*4)*192 + head*32 + ct2*16 + lr;
    #pragma unroll
    for (int r=0;r<4;r++) outp[rb + (size_t)r*192] = f2b(o[r]);
  }
}

// un-window (+unroll +crop) + LN + residual; writes fp32 trunk + bf16 copy
__global__ __launch_bounds__(256) void unwin_ln(
  const unsigned short* __restrict__ ywin,
  const float* __restrict__ xsrc,
  const float* __restrict__ g, const float* __restrict__ bb,
  float* __restrict__ outf, unsigned short* __restrict__ outb, int roll)
{
  int tok = blockIdx.x*4 + (threadIdx.x>>6);
  if (tok >= NTOK) return;
  int lane = threadIdx.x & 63;
  int z = tok / (91*180);
  int rem = tok % (91*180);
  int h = rem / 180, wc = rem % 180;
  int zz=z, hh=h, ww=wc;
  if (roll){ zz = (z+7)&7; hh = (h+93)%96; ww = (wc+174)%180; }
  int nz = zz>>1, wz = zz&1;
  int nh = hh/6,  wh = hh%6;
  int nw = ww/12, w2 = ww%12;
  size_t row = ((size_t)(nw*64 + nz*16 + nh))*144 + wz*72 + wh*12 + w2;
  const unsigned short* yr = ywin + row*192;
  float v[3]; float s=0.f, ss=0.f;
  #pragma unroll
  for (int i=0;i<3;i++){ v[i] = b2f(yr[lane + i*64]); s += v[i]; ss += v[i]*v[i]; }
  #pragma unroll
  for (int off=32; off>=1; off>>=1){ s += __shfl_xor(s, off); ss += __shfl_xor(ss, off); }
  float mean = s * (1.0f/192.0f);
  float var = ss * (1.0f/192.0f) - mean*mean;
  float rinv = rsqrtf(var + 1e-5f);
  size_t tb = (size_t)tok*192;
  #pragma unroll
  for (int i=0;i<3;i++){
    int d = lane + i*64;
    float o = xsrc[tb + d] + ((v[i]-mean)*rinv*g[d] + bb[d]);
    outf[tb+d] = o;
    outb[tb+d] = f2b(o);
  }
}

// fused MLP: C = gelu(A @ W1 + b1) @ W2 + b2
// 64 rows/block, 4 waves; each wave owns 16 rows exclusively.
// A in registers; per-wave Hs strip (no cross-wave sync on handoff);
// weight chunks reg-prefetched one iter ahead.
__global__ __launch_bounds__(256) void mlp_fused(
    const unsigned short* __restrict__ A,    // [M][192]
    const unsigned short* __restrict__ W1t,  // [768][192]
    const float* __restrict__ bias1,         // [768]
    const unsigned short* __restrict__ W2t,  // [192][768]
    const float* __restrict__ bias2,         // [192]
    unsigned short* __restrict__ C,          // [M][192]
    int M)
{
  __shared__ unsigned short W1s[32][200];
  __shared__ unsigned short W2s[192][36];
  __shared__ unsigned short Hs[4][16][40];
  int m0 = blockIdx.x*64;
  int t = threadIdx.x, lane = t & 63, w = t >> 6;
  int lg = lane >> 4, lr = lane & 15;

  // A fragments (row = m0 + w*16 + lr, k = ks*32 + lg*8..+7), kept in VGPRs
  int arow = m0 + w*16 + lr;
  bf16x8 afr[6];
  if (arow < M){
    const unsigned short* ap = A + (size_t)arow*192 + lg*8;
    #pragma unroll
    for (int ks=0; ks<6; ks++) afr[ks] = *(const bf16x8*)(ap + ks*32);
  } else {
    #pragma unroll
    for (int ks=0; ks<6; ks++)
      #pragma unroll
      for (int j=0;j<8;j++) afr[ks][j] = 0;
  }

  // staging thread mapping
  int i1r[3], i1c[3], i2r[3], i2c[3];
  #pragma unroll
  for (int i=0;i<3;i++){
    int idx = t + i*256;
    i1r[i] = idx/24; i1c[i] = (idx%24)*8;
    i2r[i] = idx/4;  i2c[i] = (idx&3)*8;
  }

  // prefetch iter 0
  u16x8 w1r[3], w2r[3];
  #pragma unroll
  for (int i=0;i<3;i++){
    w1r[i] = *(const u16x8*)(W1t + (size_t)i1r[i]*192 + i1c[i]);
    w2r[i] = *(const u16x8*)(W2t + (size_t)i2r[i]*768 + i2c[i]);
  }

  f32x4 acc[12];
  #pragma unroll
  for (int i=0;i<12;i++) acc[i] = (f32x4){0.f,0.f,0.f,0.f};

  for (int it=0; it<24; ++it){
    int hc = it*32;
    // write staged regs -> LDS
    #pragma unroll
    for (int i=0;i<3;i++){
      *(u16x8*)&W1s[i1r[i]][i1c[i]] = w1r[i];
      *(u16x8*)&W2s[i2r[i]][i2c[i]] = w2r[i];
    }
    // prefetch next chunk (issue early; lands while we compute)
    if (it < 23){
      int hc2 = hc + 32;
      #pragma unroll
      for (int i=0;i<3;i++){
        w1r[i] = *(const u16x8*)(W1t + (size_t)(hc2 + i1r[i])*192 + i1c[i]);
        w2r[i] = *(const u16x8*)(W2t + (size_t)i2r[i]*768 + hc2 + i2c[i]);
      }
    }
    __syncthreads();

    // h[16 rows][32 hidden] = A @ W1chunk
    f32x4 h0 = (f32x4){0.f,0.f,0.f,0.f};
    f32x4 h1 = (f32x4){0.f,0.f,0.f,0.f};
    #pragma unroll
    for (int ks=0; ks<6; ks++){
      bf16x8 b0 = *(const bf16x8*)&W1s[lr][ks*32 + lg*8];
      bf16x8 b1f = *(const bf16x8*)&W1s[16 + lr][ks*32 + lg*8];
      h0 = __builtin_amdgcn_mfma_f32_16x16x32_bf16(afr[ks], b0, h0, 0,0,0);
      h1 = __builtin_amdgcn_mfma_f32_16x16x32_bf16(afr[ks], b1f, h1, 0,0,0);
    }
    // gelu + per-wave Hs write (intra-wave only; no barrier)
    float bb0 = bias1[hc + lr];
    float bb1 = bias1[hc + 16 + lr];
    #pragma unroll
    for (int r=0;r<4;r++){
      Hs[w][lg*4 + r][lr]      = f2b(gelu_tanh(h0[r] + bb0));
      Hs[w][lg*4 + r][16 + lr] = f2b(gelu_tanh(h1[r] + bb1));
    }
    // read back as A-frag of gemm2 (same wave -> lgkmcnt-ordered)
    bf16x8 pa = *(const bf16x8*)&Hs[w][lr][lg*8];
    #pragma unroll
    for (int fn=0; fn<12; fn++){
      bf16x8 bb = *(const bf16x8*)&W2s[fn*16 + lr][lg*8];
      acc[fn] = __builtin_amdgcn_mfma_f32_16x16x32_bf16(pa, bb, acc[fn], 0,0,0);
    }
    __syncthreads();
  }

  #pragma unroll
  for (int fn=0; fn<12; fn++){
    float b2v = bias2[fn*16 + lr];
    #pragma unroll
    for (int r=0;r<4;r++){
      int crow = m0 + w*16 + lg*4 + r;
      if (crow < M) C[(size_t)crow*192 + fn*16 + lr] = f2b(acc[fn][r] + b2v);
    }
  }
}

// out = xmid + LN(ymlp)
__global__ __launch_bounds__(256) void add_ln(
  const unsigned short* __restrict__ ymlp,
  const float* __restrict__ xmid,
  const float* __restrict__ g, const float* __restrict__ bb,
  float* __restrict__ outf)
{
  int tok = blockIdx.x*4 + (threadIdx.x>>6);
  if (tok >= NTOK) return;
  int lane = threadIdx.x & 63;
  const unsigned short* yr = ymlp + (size_t)tok*192;
  float v[3]; float s=0.f, ss=0.f;
  #pragma unroll
  for (int i=0;i<3;i++){ v[i] = b2f(yr[lane + i*64]); s += v[i]; ss += v[i]*v[i]; }
  #pragma unroll
  for (int off=32; off>=1; off>>=1){ s += __shfl_xor(s, off); ss += __shfl_xor(ss, off); }
  float mean = s * (1.0f/192.0f);
  float var = ss * (1.0f/192.0f) - mean*mean;
  float rinv = rsqrtf(var + 1e-5f);
  size_t tb = (size_t)tok*192;
  #pragma unroll
  for (int i=0;i<3;i++){
    int d = lane + i*64;
    outf[tb+d] = xmid[tb + d] + ((v[i]-mean)*rinv*g[d] + bb[d]);
  }
}

extern "C" void kernel_launch(void* const* d_in, const int* in_sizes, int n_in,
                              void* d_out, int out_size, void* d_ws, size_t ws_size,
                              hipStream_t stream)
{
  const float* x_in    = (const float*)d_in[0];
  const float* qkvw    = (const float*)d_in[1];
  const float* qkvbias = (const float*)d_in[2];
  const float* projw   = (const float*)d_in[3];
  const float* projbias= (const float*)d_in[4];
  const float* btab    = (const float*)d_in[5];
  const float* n1g = (const float*)d_in[6];
  const float* n1b = (const float*)d_in[7];
  const float* n2g = (const float*)d_in[8];
  const float* n2b = (const float*)d_in[9];
  const float* w1  = (const float*)d_in[10];
  const float* b1  = (const float*)d_in[11];
  const float* w2  = (const float*)d_in[12];
  const float* b2  = (const float*)d_in[13];
  float* outp = (float*)d_out;

  // workspace layout (shorts)
  const size_t REG_A = (size_t)NTOKW*192;
  const size_t REG_B = (size_t)NTOKW*576;
  const size_t W_QT  = (size_t)2*576*192;
  const size_t W_PT  = (size_t)2*192*192;
  const size_t W_1T  = (size_t)2*768*192;
  const size_t W_2T  = (size_t)2*192*768;
  const size_t TOT_SH = REG_A + REG_B + W_QT + W_PT + W_1T + W_2T;
  const size_t NEEDED = TOT_SH*2 + (size_t)NTOK*192*4;
  if (ws_size < NEEDED) return;

  unsigned short* ws16 = (unsigned short*)d_ws;
  size_t off = 0;
  unsigned short* regA = ws16 + off; off += REG_A;   // xw / attn-out / xmidb
  unsigned short* regB = ws16 + off; off += REG_B;   // qkv-out / proj-out / mlp-out
  unsigned short* wqt  = ws16 + off; off += W_QT;
  unsigned short* wpt  = ws16 + off; off += W_PT;
  unsigned short* w1t  = ws16 + off; off += W_1T;
  unsigned short* w2t  = ws16 + off; off += W_2T;
  float* xmidf = (float*)(ws16 + off);
  unsigned short* bw = (unsigned short*)xmidf;   // alias: dead before unwin_ln writes

  for (int dep=0; dep<2; dep++){
    transp<<<(192*576+255)/256,256,0,stream>>>(qkvw + (size_t)dep*192*576,
                                               wqt + (size_t)dep*576*192, 192, 576);
    transp<<<(192*192+255)/256,256,0,stream>>>(projw + (size_t)dep*192*192,
                                               wpt + (size_t)dep*192*192, 192, 192);
    transp<<<(192*768+255)/256,256,0,stream>>>(w1 + (size_t)dep*192*768,
                                               w1t + (size_t)dep*768*192, 192, 768);
    transp<<<(768*192+255)/256,256,0,stream>>>(w2 + (size_t)dep*768*192,
                                               w2t + (size_t)dep*192*768, 768, 192);
  }

  for (int dep=0; dep<2; dep++){
    int roll = dep;
    const float* xs = (dep==0) ? x_in : outp;   // d_out holds block-0 trunk
    float* xout = outp;

    gather_win<<<NTOKW*24/256, 256, 0, stream>>>(xs, regA, roll);

    dim3 g1(NTOKW/128, 576/64);
    gemm_bf16<<<g1, 256, 0, stream>>>(regA, wqt + (size_t)dep*576*192,
                                      qkvbias + dep*576, regB, NTOKW, 576, 192);

    bias_pre<<<(64*6*20736)/256, 256, 0, stream>>>(btab + (size_t)dep*3312*384, bw, roll);

    attn_win<<<960*6, 576, 0, stream>>>(regB, bw, regA);

    dim3 g2(NTOKW/128, 192/64);
    gemm_bf16<<<g2, 256, 0, stream>>>(regA, wpt + (size_t)dep*192*192,
                                      projbias + dep*192, regB, NTOKW, 192, 192);

    unwin_ln<<<NTOK/4, 256, 0, stream>>>(regB, xs, n1g + dep*192, n1b + dep*192,
                                         xmidf, regA, roll);

    mlp_fused<<<(NTOK+63)/64, 256, 0, stream>>>(regA, w1t + (size_t)dep*768*192,
                                                b1 + dep*768, w2t + (size_t)dep*192*768,
                                                b2 + dep*192, regB, NTOK);

    add_ln<<<NTOK/4, 256, 0, stream>>>(regB, xmidf, n2g + dep*192, n2b + dep*192, xout);
  }
}